// Round 4
// baseline (1199.881 us; speedup 1.0000x reference)
//
#include <hip/hip_runtime.h>

// rAdjConv: out[dst] += x[src] / edge_div over 64 features per edge.
// Round 4: bucket-binned LDS gather.
//   deg -> alpha = rsqrt(deg);  out[d] = alpha[d] * sum alpha[s]*x[s]
//   Pass B: bin edges by dst bucket (64 nodes/bucket), packed (dstLocal<<18|src).
//   Pass C: one block per bucket, LDS float accumulators, ds_add_f32 per edge,
//           coalesced store with final *alpha[d]. x prescaled by alpha[s] into
//           bf16 (halves gather traffic) when ws allows; f32 variant otherwise.

constexpr int D_FEAT = 64;
constexpr int NPB    = 64;     // nodes per bucket (local dst fits in 6 bits)
constexpr int SCAN_B = 1024;

__device__ __forceinline__ unsigned short f2bf(float v) {
    unsigned u = __float_as_uint(v);
    return (unsigned short)((u + 0x7fffu + ((u >> 16) & 1u)) >> 16);
}
__device__ __forceinline__ float bf2f(unsigned short u) {
    return __uint_as_float(((unsigned)u) << 16);
}

// ---------- fallback (round-1 atomic scatter) ----------
__global__ void radj_scatter_kernel(const float* __restrict__ x,
                                    const int* __restrict__ edge_src,
                                    const int* __restrict__ edge_dst,
                                    const float* __restrict__ edge_div,
                                    float* __restrict__ out,
                                    int nedges) {
    long long tid = (long long)blockIdx.x * blockDim.x + threadIdx.x;
    long long total = (long long)nedges * 16;
    if (tid >= total) return;
    int e  = (int)(tid >> 4);
    int fg = (int)(tid & 15) << 2;
    int s = edge_src[e];
    int d = edge_dst[e];
    float inv = 1.0f / edge_div[e];
    const float4 v = *reinterpret_cast<const float4*>(x + (long long)s * D_FEAT + fg);
    float* o = out + (long long)d * D_FEAT + fg;
    atomicAdd(o + 0, v.x * inv);
    atomicAdd(o + 1, v.y * inv);
    atomicAdd(o + 2, v.z * inv);
    atomicAdd(o + 3, v.w * inv);
}

// ---------- degree + scan ----------
__global__ void count_deg(const int* __restrict__ dst, int* __restrict__ deg, int n) {
    int gid = blockIdx.x * blockDim.x + threadIdx.x;
    if (gid < n) atomicAdd(&deg[dst[gid]], 1);
}

__global__ void scan_block(const int* __restrict__ in, int* __restrict__ incl,
                           int* __restrict__ bsums, int n) {
    __shared__ int tmp[SCAN_B];
    int gid = blockIdx.x * SCAN_B + threadIdx.x;
    int v = (gid < n) ? in[gid] : 0;
    tmp[threadIdx.x] = v;
    __syncthreads();
    for (int ofs = 1; ofs < SCAN_B; ofs <<= 1) {
        int t = (threadIdx.x >= ofs) ? tmp[threadIdx.x - ofs] : 0;
        __syncthreads();
        tmp[threadIdx.x] += t;
        __syncthreads();
    }
    if (gid < n) incl[gid] = tmp[threadIdx.x];
    if (bsums && threadIdx.x == SCAN_B - 1) bsums[blockIdx.x] = tmp[SCAN_B - 1];
}

__global__ void scan_finalize(const int* __restrict__ deg, const int* __restrict__ incl,
                              const int* __restrict__ bsums_incl,
                              int* __restrict__ off, float* __restrict__ alpha, int n) {
    int gid = blockIdx.x * SCAN_B + threadIdx.x;
    if (gid >= n) return;
    int boff = (blockIdx.x > 0) ? bsums_incl[blockIdx.x - 1] : 0;
    int d = deg[gid];
    int e = incl[gid] - d + boff;
    off[gid] = e;
    alpha[gid] = rsqrtf(fmaxf((float)d, 1.0f));
    if (gid == n - 1) off[n] = e + d;
}

__global__ void init_bcur(const int* __restrict__ off, int* __restrict__ cur_b, int nb) {
    int b = blockIdx.x * blockDim.x + threadIdx.x;
    if (b < nb) cur_b[b] = off[b * NPB];
}

// ---------- prescale x by alpha[src], cast to bf16 ----------
__global__ void prescale_bf16(const float4* __restrict__ x4,
                              const float* __restrict__ alpha,
                              ushort4* __restrict__ xs4, int n4) {
    int g = blockIdx.x * blockDim.x + threadIdx.x;
    if (g >= n4) return;
    float a = alpha[g >> 4];          // 16 float4 groups per node row
    float4 v = x4[g];
    ushort4 o;
    o.x = f2bf(v.x * a);
    o.y = f2bf(v.y * a);
    o.z = f2bf(v.z * a);
    o.w = f2bf(v.w * a);
    xs4[g] = o;
}

// ---------- bin fill: packed (dstLocal<<18 | src) appended per bucket ----------
__global__ void bin_fill(const int* __restrict__ src, const int* __restrict__ dst,
                         int* __restrict__ cur_b, unsigned* __restrict__ binned, int n) {
    int gid = blockIdx.x * blockDim.x + threadIdx.x;
    if (gid >= n) return;
    int d = dst[gid];
    int pos = atomicAdd(&cur_b[d >> 6], 1);
    binned[pos] = ((unsigned)(d & 63) << 18) | (unsigned)src[gid];
}

// ---------- bucket gather: one block per bucket, LDS accumulators ----------
__global__ __launch_bounds__(256) void bucket_gather_bf16(
    const unsigned short* __restrict__ xs,
    const float* __restrict__ alpha,
    const int* __restrict__ off,
    const unsigned* __restrict__ binned,
    float* __restrict__ out, int nnodes) {
    __shared__ float acc[NPB * D_FEAT];
    int lo = blockIdx.x * NPB;
    int hi = lo + NPB; if (hi > nnodes) hi = nnodes;
    for (int t = threadIdx.x; t < NPB * D_FEAT; t += 256) acc[t] = 0.0f;
    __syncthreads();
    int beg = off[lo], end = off[hi];
    int wave = threadIdx.x >> 6, lane = threadIdx.x & 63;
    int i = beg + wave;
    for (; i + 12 < end; i += 16) {
        unsigned p0 = binned[i];
        unsigned p1 = binned[i + 4];
        unsigned p2 = binned[i + 8];
        unsigned p3 = binned[i + 12];
        float v0 = bf2f(xs[(size_t)(p0 & 0x3ffffu) * D_FEAT + lane]);
        float v1 = bf2f(xs[(size_t)(p1 & 0x3ffffu) * D_FEAT + lane]);
        float v2 = bf2f(xs[(size_t)(p2 & 0x3ffffu) * D_FEAT + lane]);
        float v3 = bf2f(xs[(size_t)(p3 & 0x3ffffu) * D_FEAT + lane]);
        atomicAdd(&acc[(p0 >> 18) * D_FEAT + lane], v0);
        atomicAdd(&acc[(p1 >> 18) * D_FEAT + lane], v1);
        atomicAdd(&acc[(p2 >> 18) * D_FEAT + lane], v2);
        atomicAdd(&acc[(p3 >> 18) * D_FEAT + lane], v3);
    }
    for (; i < end; i += 4) {
        unsigned p = binned[i];
        float v = bf2f(xs[(size_t)(p & 0x3ffffu) * D_FEAT + lane]);
        atomicAdd(&acc[(p >> 18) * D_FEAT + lane], v);
    }
    __syncthreads();
    int nelem = (hi - lo) * D_FEAT;
    for (int t = threadIdx.x; t < nelem; t += 256) {
        int r = t >> 6;
        out[(size_t)(lo + r) * D_FEAT + (t & 63)] = acc[t] * alpha[lo + r];
    }
}

__global__ __launch_bounds__(256) void bucket_gather_f32(
    const float* __restrict__ x,
    const float* __restrict__ alpha,
    const int* __restrict__ off,
    const unsigned* __restrict__ binned,
    float* __restrict__ out, int nnodes) {
    __shared__ float acc[NPB * D_FEAT];
    int lo = blockIdx.x * NPB;
    int hi = lo + NPB; if (hi > nnodes) hi = nnodes;
    for (int t = threadIdx.x; t < NPB * D_FEAT; t += 256) acc[t] = 0.0f;
    __syncthreads();
    int beg = off[lo], end = off[hi];
    int wave = threadIdx.x >> 6, lane = threadIdx.x & 63;
    int i = beg + wave;
    for (; i + 12 < end; i += 16) {
        unsigned p0 = binned[i];
        unsigned p1 = binned[i + 4];
        unsigned p2 = binned[i + 8];
        unsigned p3 = binned[i + 12];
        unsigned s0 = p0 & 0x3ffffu, s1 = p1 & 0x3ffffu, s2 = p2 & 0x3ffffu, s3 = p3 & 0x3ffffu;
        float v0 = x[(size_t)s0 * D_FEAT + lane] * alpha[s0];
        float v1 = x[(size_t)s1 * D_FEAT + lane] * alpha[s1];
        float v2 = x[(size_t)s2 * D_FEAT + lane] * alpha[s2];
        float v3 = x[(size_t)s3 * D_FEAT + lane] * alpha[s3];
        atomicAdd(&acc[(p0 >> 18) * D_FEAT + lane], v0);
        atomicAdd(&acc[(p1 >> 18) * D_FEAT + lane], v1);
        atomicAdd(&acc[(p2 >> 18) * D_FEAT + lane], v2);
        atomicAdd(&acc[(p3 >> 18) * D_FEAT + lane], v3);
    }
    for (; i < end; i += 4) {
        unsigned p = binned[i];
        unsigned s = p & 0x3ffffu;
        float v = x[(size_t)s * D_FEAT + lane] * alpha[s];
        atomicAdd(&acc[(p >> 18) * D_FEAT + lane], v);
    }
    __syncthreads();
    int nelem = (hi - lo) * D_FEAT;
    for (int t = threadIdx.x; t < nelem; t += 256) {
        int r = t >> 6;
        out[(size_t)(lo + r) * D_FEAT + (t & 63)] = acc[t] * alpha[lo + r];
    }
}

extern "C" void kernel_launch(void* const* d_in, const int* in_sizes, int n_in,
                              void* d_out, int out_size, void* d_ws, size_t ws_size,
                              hipStream_t stream) {
    const float* x        = (const float*)d_in[0];
    const int*   edge_src = (const int*)d_in[1];
    const int*   edge_dst = (const int*)d_in[2];
    const float* edge_div = (const float*)d_in[3];
    float* out = (float*)d_out;

    int nedges = in_sizes[1];            // 2E
    int nnodes = out_size / D_FEAT;      // N_NODES
    int nb     = (nnodes + NPB - 1) / NPB;

    size_t words_f32  = (size_t)4 * nnodes + 1 + 1024 + nb + (size_t)nedges;
    size_t need_f32   = words_f32 * 4;
    size_t need_bf16  = need_f32 + (size_t)nnodes * D_FEAT * 2;

    if (ws_size < need_f32) {
        hipMemsetAsync(out, 0, (size_t)out_size * sizeof(float), stream);
        long long total = (long long)nedges * 16;
        radj_scatter_kernel<<<(int)((total + 255) / 256), 256, 0, stream>>>(
            x, edge_src, edge_dst, edge_div, out, nedges);
        return;
    }
    bool use_bf16 = (ws_size >= need_bf16);

    int*      deg    = (int*)d_ws;                    // nnodes
    int*      incl   = deg + nnodes;                  // nnodes
    int*      off    = incl + nnodes;                 // nnodes + 1
    float*    alpha  = (float*)(off + nnodes + 1);    // nnodes
    int*      bsums  = (int*)(alpha + nnodes);        // 1024
    int*      cur_b  = bsums + 1024;                  // nb
    unsigned* binned = (unsigned*)(cur_b + nb);       // nedges
    unsigned short* xs = (unsigned short*)(binned + nedges);  // nnodes*64 bf16

    int nblk = (nnodes + SCAN_B - 1) / SCAN_B;

    hipMemsetAsync(deg, 0, (size_t)nnodes * sizeof(int), stream);

    count_deg<<<(nedges + 255) / 256, 256, 0, stream>>>(edge_dst, deg, nedges);

    scan_block<<<nblk, SCAN_B, 0, stream>>>(deg, incl, bsums, nnodes);
    scan_block<<<1, SCAN_B, 0, stream>>>(bsums, bsums, nullptr, nblk);
    scan_finalize<<<nblk, SCAN_B, 0, stream>>>(deg, incl, bsums, off, alpha, nnodes);

    init_bcur<<<(nb + 255) / 256, 256, 0, stream>>>(off, cur_b, nb);

    bin_fill<<<(nedges + 255) / 256, 256, 0, stream>>>(
        edge_src, edge_dst, cur_b, binned, nedges);

    if (use_bf16) {
        int n4 = nnodes * (D_FEAT / 4);
        prescale_bf16<<<(n4 + 255) / 256, 256, 0, stream>>>(
            (const float4*)x, alpha, (ushort4*)xs, n4);
        bucket_gather_bf16<<<nb, 256, 0, stream>>>(xs, alpha, off, binned, out, nnodes);
    } else {
        bucket_gather_f32<<<nb, 256, 0, stream>>>(x, alpha, off, binned, out, nnodes);
    }
}

// Round 5
// 242.351 us; speedup vs baseline: 4.9510x; 4.9510x over previous
//
#include <hip/hip_runtime.h>

// rAdjConv: out[dst] += x[src] / edge_div over 64 features per edge.
// Round 5: alpha = rsqrt(deg); out[d] = alpha[d] * sum alpha[s]*x[s].
//   count_deg -> scan (off, alpha)
//   bin_edges: block-aggregated coarse binning (256-node buckets), contiguous runs
//   build_csr: one block per bucket, LDS cursors, exact CSR (single-XCD writes)
//   gather: one wave per node, lane = feature, bf16-prescaled x (xs), unroll 4

constexpr int D_FEAT = 64;
constexpr int SCAN_B = 1024;
constexpr int BSH    = 8;            // 256 nodes per bucket
constexpr int NPBKT  = 1 << BSH;
constexpr int MAXB   = 1024;         // max buckets (nnodes <= 262144)
constexpr int BIN_T  = 256;
constexpr int BIN_K  = 32;
constexpr int EPB    = BIN_T * BIN_K;  // 8192 edges per bin block

__device__ __forceinline__ unsigned short f2bf(float v) {
    unsigned u = __float_as_uint(v);
    return (unsigned short)((u + 0x7fffu + ((u >> 16) & 1u)) >> 16);
}
__device__ __forceinline__ float bf2f(unsigned short u) {
    return __uint_as_float(((unsigned)u) << 16);
}

// ---------- fallback (round-1 atomic scatter) ----------
__global__ void radj_scatter_kernel(const float* __restrict__ x,
                                    const int* __restrict__ edge_src,
                                    const int* __restrict__ edge_dst,
                                    const float* __restrict__ edge_div,
                                    float* __restrict__ out,
                                    int nedges) {
    long long tid = (long long)blockIdx.x * blockDim.x + threadIdx.x;
    long long total = (long long)nedges * 16;
    if (tid >= total) return;
    int e  = (int)(tid >> 4);
    int fg = (int)(tid & 15) << 2;
    int s = edge_src[e];
    int d = edge_dst[e];
    float inv = 1.0f / edge_div[e];
    const float4 v = *reinterpret_cast<const float4*>(x + (long long)s * D_FEAT + fg);
    float* o = out + (long long)d * D_FEAT + fg;
    atomicAdd(o + 0, v.x * inv);
    atomicAdd(o + 1, v.y * inv);
    atomicAdd(o + 2, v.z * inv);
    atomicAdd(o + 3, v.w * inv);
}

// ---------- degree + scan ----------
__global__ void count_deg(const int* __restrict__ dst, int* __restrict__ deg, int n) {
    int gid = blockIdx.x * blockDim.x + threadIdx.x;
    if (gid < n) atomicAdd(&deg[dst[gid]], 1);
}

__global__ void scan_block(const int* __restrict__ in, int* __restrict__ incl,
                           int* __restrict__ bsums, int n) {
    __shared__ int tmp[SCAN_B];
    int gid = blockIdx.x * SCAN_B + threadIdx.x;
    int v = (gid < n) ? in[gid] : 0;
    tmp[threadIdx.x] = v;
    __syncthreads();
    for (int ofs = 1; ofs < SCAN_B; ofs <<= 1) {
        int t = (threadIdx.x >= ofs) ? tmp[threadIdx.x - ofs] : 0;
        __syncthreads();
        tmp[threadIdx.x] += t;
        __syncthreads();
    }
    if (gid < n) incl[gid] = tmp[threadIdx.x];
    if (bsums && threadIdx.x == SCAN_B - 1) bsums[blockIdx.x] = tmp[SCAN_B - 1];
}

__global__ void scan_finalize(const int* __restrict__ deg, const int* __restrict__ incl,
                              const int* __restrict__ bsums_incl,
                              int* __restrict__ off, float* __restrict__ alpha, int n) {
    int gid = blockIdx.x * SCAN_B + threadIdx.x;
    if (gid >= n) return;
    int boff = (blockIdx.x > 0) ? bsums_incl[blockIdx.x - 1] : 0;
    int d = deg[gid];
    int e = incl[gid] - d + boff;
    off[gid] = e;
    alpha[gid] = rsqrtf(fmaxf((float)d, 1.0f));
    if (gid == n - 1) off[n] = e + d;
}

__global__ void init_gcur(const int* __restrict__ off, int* __restrict__ gcur,
                          int nbkt, int nnodes) {
    int b = blockIdx.x * blockDim.x + threadIdx.x;
    if (b < nbkt) {
        int lo = b << BSH;
        gcur[b] = off[lo < nnodes ? lo : nnodes];
    }
}

// ---------- prescale x by alpha[src], cast to bf16 ----------
__global__ void prescale_bf16(const float4* __restrict__ x4,
                              const float* __restrict__ alpha,
                              ushort4* __restrict__ xs4, int n4) {
    int g = blockIdx.x * blockDim.x + threadIdx.x;
    if (g >= n4) return;
    float a = alpha[g >> 4];
    float4 v = x4[g];
    ushort4 o;
    o.x = f2bf(v.x * a);
    o.y = f2bf(v.y * a);
    o.z = f2bf(v.z * a);
    o.w = f2bf(v.w * a);
    xs4[g] = o;
}

// ---------- pass B: block-aggregated coarse binning ----------
// binned entry = (dstLocal<<18) | src  (src < 2^18, dstLocal < 256)
__global__ __launch_bounds__(BIN_T) void bin_edges(
    const int* __restrict__ src, const int* __restrict__ dst,
    int* __restrict__ gcur, unsigned* __restrict__ binned, int n, int nbkt) {
    __shared__ int hist[MAXB];
    __shared__ int base[MAXB];
    __shared__ unsigned einfo[EPB];   // (b<<13) | rank
    for (int t = threadIdx.x; t < nbkt; t += BIN_T) hist[t] = 0;
    __syncthreads();
    long long e0 = (long long)blockIdx.x * EPB;
#pragma unroll
    for (int k = 0; k < BIN_K; ++k) {
        long long e = e0 + (long long)k * BIN_T + threadIdx.x;
        if (e < n) {
            int b = dst[e] >> BSH;
            int rank = atomicAdd(&hist[b], 1);
            einfo[k * BIN_T + threadIdx.x] = ((unsigned)b << 13) | (unsigned)rank;
        }
    }
    __syncthreads();
    for (int t = threadIdx.x; t < nbkt; t += BIN_T) {
        int h = hist[t];
        base[t] = h ? atomicAdd(&gcur[t], h) : 0;
    }
    __syncthreads();
#pragma unroll
    for (int k = 0; k < BIN_K; ++k) {
        long long e = e0 + (long long)k * BIN_T + threadIdx.x;
        if (e < n) {
            int d = dst[e];
            int s = src[e];
            unsigned info = einfo[k * BIN_T + threadIdx.x];
            int b = info >> 13;
            int rank = info & 0x1fff;
            binned[base[b] + rank] = ((unsigned)(d & (NPBKT - 1)) << 18) | (unsigned)s;
        }
    }
}

// ---------- pass C: exact CSR, one block per bucket (single-XCD writes) ----------
__global__ __launch_bounds__(NPBKT) void build_csr(
    const int* __restrict__ off, const unsigned* __restrict__ binned,
    unsigned* __restrict__ csr, int nnodes) {
    __shared__ int cur[NPBKT];
    int lo = blockIdx.x << BSH;
    int hi = lo + NPBKT; if (hi > nnodes) hi = nnodes;
    if (lo + (int)threadIdx.x < hi) cur[threadIdx.x] = off[lo + threadIdx.x];
    __syncthreads();
    int beg = off[lo], end = off[hi];
    for (int i = beg + threadIdx.x; i < end; i += NPBKT) {
        unsigned p = binned[i];
        int dl = p >> 18;
        int pos = atomicAdd(&cur[dl], 1);
        csr[pos] = p & 0x3ffffu;
    }
}

// ---------- gather: one wave per node, lane = feature ----------
__global__ void gather_bf16(const unsigned short* __restrict__ xs,
                            const float* __restrict__ alpha,
                            const int* __restrict__ off,
                            const unsigned* __restrict__ csr,
                            float* __restrict__ out, int nnodes) {
    int wid = (blockIdx.x * blockDim.x + threadIdx.x) >> 6;
    int lane = threadIdx.x & 63;
    if (wid >= nnodes) return;
    int beg = off[wid], end = off[wid + 1];
    float acc = 0.0f;
    int i = beg;
    for (; i + 4 <= end; i += 4) {
        unsigned s0 = csr[i + 0], s1 = csr[i + 1], s2 = csr[i + 2], s3 = csr[i + 3];
        float v0 = bf2f(xs[(size_t)s0 * D_FEAT + lane]);
        float v1 = bf2f(xs[(size_t)s1 * D_FEAT + lane]);
        float v2 = bf2f(xs[(size_t)s2 * D_FEAT + lane]);
        float v3 = bf2f(xs[(size_t)s3 * D_FEAT + lane]);
        acc += v0; acc += v1; acc += v2; acc += v3;
    }
    for (; i < end; ++i)
        acc += bf2f(xs[(size_t)csr[i] * D_FEAT + lane]);
    out[(size_t)wid * D_FEAT + lane] = acc * alpha[wid];
}

__global__ void gather_f32(const float* __restrict__ x,
                           const float* __restrict__ alpha,
                           const int* __restrict__ off,
                           const unsigned* __restrict__ csr,
                           float* __restrict__ out, int nnodes) {
    int wid = (blockIdx.x * blockDim.x + threadIdx.x) >> 6;
    int lane = threadIdx.x & 63;
    if (wid >= nnodes) return;
    int beg = off[wid], end = off[wid + 1];
    float acc = 0.0f;
    int i = beg;
    for (; i + 4 <= end; i += 4) {
        unsigned s0 = csr[i + 0], s1 = csr[i + 1], s2 = csr[i + 2], s3 = csr[i + 3];
        float a0 = alpha[s0], a1 = alpha[s1], a2 = alpha[s2], a3 = alpha[s3];
        float v0 = x[(size_t)s0 * D_FEAT + lane];
        float v1 = x[(size_t)s1 * D_FEAT + lane];
        float v2 = x[(size_t)s2 * D_FEAT + lane];
        float v3 = x[(size_t)s3 * D_FEAT + lane];
        acc += v0 * a0; acc += v1 * a1; acc += v2 * a2; acc += v3 * a3;
    }
    for (; i < end; ++i) {
        unsigned s = csr[i];
        acc += x[(size_t)s * D_FEAT + lane] * alpha[s];
    }
    out[(size_t)wid * D_FEAT + lane] = acc * alpha[wid];
}

extern "C" void kernel_launch(void* const* d_in, const int* in_sizes, int n_in,
                              void* d_out, int out_size, void* d_ws, size_t ws_size,
                              hipStream_t stream) {
    const float* x        = (const float*)d_in[0];
    const int*   edge_src = (const int*)d_in[1];
    const int*   edge_dst = (const int*)d_in[2];
    const float* edge_div = (const float*)d_in[3];
    float* out = (float*)d_out;

    int nedges = in_sizes[1];            // 2E
    int nnodes = out_size / D_FEAT;      // N_NODES
    int nbkt   = (nnodes + NPBKT - 1) >> BSH;

    // ws words: deg n, incl n, off n+1, alpha n, bsums 1024, gcur MAXB,
    //           binned E, csr E  [+ xs = 32n words for bf16 path]
    size_t base_words = (size_t)4 * nnodes + 1 + 1024 + MAXB + 2 * (size_t)nedges;
    size_t need_f32   = base_words * 4;
    size_t need_bf16  = need_f32 + (size_t)nnodes * D_FEAT * 2;

    if (nnodes > 262144 || nbkt > MAXB || ws_size < need_f32) {
        hipMemsetAsync(out, 0, (size_t)out_size * sizeof(float), stream);
        long long total = (long long)nedges * 16;
        radj_scatter_kernel<<<(int)((total + 255) / 256), 256, 0, stream>>>(
            x, edge_src, edge_dst, edge_div, out, nedges);
        return;
    }
    bool use_bf16 = (ws_size >= need_bf16);

    int*      deg    = (int*)d_ws;                   // n
    int*      incl   = deg + nnodes;                 // n
    int*      off    = incl + nnodes;                // n+1
    float*    alpha  = (float*)(off + nnodes + 1);   // n
    int*      bsums  = (int*)(alpha + nnodes);       // 1024
    int*      gcur   = bsums + 1024;                 // MAXB
    unsigned* binned = (unsigned*)(gcur + MAXB);     // E
    unsigned* csr    = binned + nedges;              // E
    unsigned short* xs = (unsigned short*)(csr + nedges);  // 64n bf16

    int nblk = (nnodes + SCAN_B - 1) / SCAN_B;

    hipMemsetAsync(deg, 0, (size_t)nnodes * sizeof(int), stream);

    count_deg<<<(nedges + 255) / 256, 256, 0, stream>>>(edge_dst, deg, nedges);

    scan_block<<<nblk, SCAN_B, 0, stream>>>(deg, incl, bsums, nnodes);
    scan_block<<<1, SCAN_B, 0, stream>>>(bsums, bsums, nullptr, nblk);
    scan_finalize<<<nblk, SCAN_B, 0, stream>>>(deg, incl, bsums, off, alpha, nnodes);

    init_gcur<<<(nbkt + 255) / 256, 256, 0, stream>>>(off, gcur, nbkt, nnodes);

    bin_edges<<<(nedges + EPB - 1) / EPB, BIN_T, 0, stream>>>(
        edge_src, edge_dst, gcur, binned, nedges, nbkt);

    build_csr<<<nbkt, NPBKT, 0, stream>>>(off, binned, csr, nnodes);

    long long gthreads = (long long)nnodes * 64;
    int ggrid = (int)((gthreads + 255) / 256);
    if (use_bf16) {
        int n4 = nnodes * (D_FEAT / 4);
        prescale_bf16<<<(n4 + 255) / 256, 256, 0, stream>>>(
            (const float4*)x, alpha, (ushort4*)xs, n4);
        gather_bf16<<<ggrid, 256, 0, stream>>>(xs, alpha, off, csr, out, nnodes);
    } else {
        gather_f32<<<ggrid, 256, 0, stream>>>(x, alpha, off, csr, out, nnodes);
    }
}

// Round 6
// 222.738 us; speedup vs baseline: 5.3870x; 1.0881x over previous
//
#include <hip/hip_runtime.h>

// rAdjConv: out[dst] += x[src] / edge_div over 64 features per edge.
// Round 6: alpha = rsqrt(deg); out[d] = alpha[d] * sum alpha[s]*x[s].
//   xs = bf16(alpha[s]*x[s]) placed at ws offset 0 -> 128B-aligned rows.
//   gather: one wave per node, half-wave ushort2 loads (one aligned 128B row
//   per edge per half-wave), 8 edges in flight, __shfl_xor(32) combine.

constexpr int D_FEAT = 64;
constexpr int SCAN_B = 1024;
constexpr int BSH    = 8;            // 256 nodes per bucket
constexpr int NPBKT  = 1 << BSH;
constexpr int MAXB   = 1024;         // max buckets (nnodes <= 262144)
constexpr int BIN_T  = 256;
constexpr int BIN_K  = 32;
constexpr int EPB    = BIN_T * BIN_K;  // 8192 edges per bin block

__device__ __forceinline__ unsigned short f2bf(float v) {
    unsigned u = __float_as_uint(v);
    return (unsigned short)((u + 0x7fffu + ((u >> 16) & 1u)) >> 16);
}
__device__ __forceinline__ float bf2f(unsigned short u) {
    return __uint_as_float(((unsigned)u) << 16);
}

// ---------- fallback (round-1 atomic scatter) ----------
__global__ void radj_scatter_kernel(const float* __restrict__ x,
                                    const int* __restrict__ edge_src,
                                    const int* __restrict__ edge_dst,
                                    const float* __restrict__ edge_div,
                                    float* __restrict__ out,
                                    int nedges) {
    long long tid = (long long)blockIdx.x * blockDim.x + threadIdx.x;
    long long total = (long long)nedges * 16;
    if (tid >= total) return;
    int e  = (int)(tid >> 4);
    int fg = (int)(tid & 15) << 2;
    int s = edge_src[e];
    int d = edge_dst[e];
    float inv = 1.0f / edge_div[e];
    const float4 v = *reinterpret_cast<const float4*>(x + (long long)s * D_FEAT + fg);
    float* o = out + (long long)d * D_FEAT + fg;
    atomicAdd(o + 0, v.x * inv);
    atomicAdd(o + 1, v.y * inv);
    atomicAdd(o + 2, v.z * inv);
    atomicAdd(o + 3, v.w * inv);
}

// ---------- degree + scan ----------
__global__ void count_deg(const int* __restrict__ dst, int* __restrict__ deg, int n) {
    int gid = blockIdx.x * blockDim.x + threadIdx.x;
    if (gid < n) atomicAdd(&deg[dst[gid]], 1);
}

__global__ void scan_block(const int* __restrict__ in, int* __restrict__ incl,
                           int* __restrict__ bsums, int n) {
    __shared__ int tmp[SCAN_B];
    int gid = blockIdx.x * SCAN_B + threadIdx.x;
    int v = (gid < n) ? in[gid] : 0;
    tmp[threadIdx.x] = v;
    __syncthreads();
    for (int ofs = 1; ofs < SCAN_B; ofs <<= 1) {
        int t = (threadIdx.x >= ofs) ? tmp[threadIdx.x - ofs] : 0;
        __syncthreads();
        tmp[threadIdx.x] += t;
        __syncthreads();
    }
    if (gid < n) incl[gid] = tmp[threadIdx.x];
    if (bsums && threadIdx.x == SCAN_B - 1) bsums[blockIdx.x] = tmp[SCAN_B - 1];
}

__global__ void scan_finalize(const int* __restrict__ deg, const int* __restrict__ incl,
                              const int* __restrict__ bsums_incl,
                              int* __restrict__ off, float* __restrict__ alpha, int n) {
    int gid = blockIdx.x * SCAN_B + threadIdx.x;
    if (gid >= n) return;
    int boff = (blockIdx.x > 0) ? bsums_incl[blockIdx.x - 1] : 0;
    int d = deg[gid];
    int e = incl[gid] - d + boff;
    off[gid] = e;
    alpha[gid] = rsqrtf(fmaxf((float)d, 1.0f));
    if (gid == n - 1) off[n] = e + d;
}

__global__ void init_gcur(const int* __restrict__ off, int* __restrict__ gcur,
                          int nbkt, int nnodes) {
    int b = blockIdx.x * blockDim.x + threadIdx.x;
    if (b < nbkt) {
        int lo = b << BSH;
        gcur[b] = off[lo < nnodes ? lo : nnodes];
    }
}

// ---------- prescale x by alpha[src], cast to bf16 ----------
__global__ void prescale_bf16(const float4* __restrict__ x4,
                              const float* __restrict__ alpha,
                              ushort4* __restrict__ xs4, int n4) {
    int g = blockIdx.x * blockDim.x + threadIdx.x;
    if (g >= n4) return;
    float a = alpha[g >> 4];
    float4 v = x4[g];
    ushort4 o;
    o.x = f2bf(v.x * a);
    o.y = f2bf(v.y * a);
    o.z = f2bf(v.z * a);
    o.w = f2bf(v.w * a);
    xs4[g] = o;
}

// ---------- pass B: block-aggregated coarse binning ----------
// binned entry = (dstLocal<<18) | src  (src < 2^18, dstLocal < 256)
__global__ __launch_bounds__(BIN_T) void bin_edges(
    const int* __restrict__ src, const int* __restrict__ dst,
    int* __restrict__ gcur, unsigned* __restrict__ binned, int n, int nbkt) {
    __shared__ int hist[MAXB];
    __shared__ int base[MAXB];
    __shared__ unsigned einfo[EPB];   // (b<<13) | rank
    for (int t = threadIdx.x; t < nbkt; t += BIN_T) hist[t] = 0;
    __syncthreads();
    long long e0 = (long long)blockIdx.x * EPB;
#pragma unroll
    for (int k = 0; k < BIN_K; ++k) {
        long long e = e0 + (long long)k * BIN_T + threadIdx.x;
        if (e < n) {
            int b = dst[e] >> BSH;
            int rank = atomicAdd(&hist[b], 1);
            einfo[k * BIN_T + threadIdx.x] = ((unsigned)b << 13) | (unsigned)rank;
        }
    }
    __syncthreads();
    for (int t = threadIdx.x; t < nbkt; t += BIN_T) {
        int h = hist[t];
        base[t] = h ? atomicAdd(&gcur[t], h) : 0;
    }
    __syncthreads();
#pragma unroll
    for (int k = 0; k < BIN_K; ++k) {
        long long e = e0 + (long long)k * BIN_T + threadIdx.x;
        if (e < n) {
            int d = dst[e];
            int s = src[e];
            unsigned info = einfo[k * BIN_T + threadIdx.x];
            int b = info >> 13;
            int rank = info & 0x1fff;
            binned[base[b] + rank] = ((unsigned)(d & (NPBKT - 1)) << 18) | (unsigned)s;
        }
    }
}

// ---------- pass C: exact CSR, one block per bucket (single-XCD writes) ----------
__global__ __launch_bounds__(NPBKT) void build_csr(
    const int* __restrict__ off, const unsigned* __restrict__ binned,
    unsigned* __restrict__ csr, int nnodes) {
    __shared__ int cur[NPBKT];
    int lo = blockIdx.x << BSH;
    int hi = lo + NPBKT; if (hi > nnodes) hi = nnodes;
    if (lo + (int)threadIdx.x < hi) cur[threadIdx.x] = off[lo + threadIdx.x];
    __syncthreads();
    int beg = off[lo], end = off[hi];
    for (int i = beg + threadIdx.x; i < end; i += NPBKT) {
        unsigned p = binned[i];
        int dl = p >> 18;
        int pos = atomicAdd(&cur[dl], 1);
        csr[pos] = p & 0x3ffffu;
    }
}

// ---------- gather: one wave per node, half-wave ushort2 loads ----------
__global__ void gather_bf16(const unsigned short* __restrict__ xs,
                            const float* __restrict__ alpha,
                            const int* __restrict__ off,
                            const unsigned* __restrict__ csr,
                            float* __restrict__ out, int nnodes) {
    int wid = (blockIdx.x * blockDim.x + threadIdx.x) >> 6;
    if (wid >= nnodes) return;
    int lane = threadIdx.x & 63;
    int half = lane >> 5;      // 0: even edges, 1: odd edges
    int hl   = lane & 31;      // feature pair index
    int beg = off[wid], end = off[wid + 1];
    const unsigned short* xb = xs + hl * 2;
    float ax0 = 0.f, ay0 = 0.f, ax1 = 0.f, ay1 = 0.f;
    int j = beg;
    for (; j + 8 <= end; j += 8) {
        int i0 = j + half, i1 = i0 + 2, i2 = i0 + 4, i3 = i0 + 6;
        unsigned s0 = csr[i0], s1 = csr[i1], s2 = csr[i2], s3 = csr[i3];
        ushort2 u0 = *reinterpret_cast<const ushort2*>(xb + (size_t)s0 * D_FEAT);
        ushort2 u1 = *reinterpret_cast<const ushort2*>(xb + (size_t)s1 * D_FEAT);
        ushort2 u2 = *reinterpret_cast<const ushort2*>(xb + (size_t)s2 * D_FEAT);
        ushort2 u3 = *reinterpret_cast<const ushort2*>(xb + (size_t)s3 * D_FEAT);
        ax0 += bf2f(u0.x); ay0 += bf2f(u0.y);
        ax1 += bf2f(u1.x); ay1 += bf2f(u1.y);
        ax0 += bf2f(u2.x); ay0 += bf2f(u2.y);
        ax1 += bf2f(u3.x); ay1 += bf2f(u3.y);
    }
    for (; j < end; j += 2) {
        int i = j + half;
        if (i < end) {
            unsigned s = csr[i];
            ushort2 u = *reinterpret_cast<const ushort2*>(xb + (size_t)s * D_FEAT);
            ax0 += bf2f(u.x); ay0 += bf2f(u.y);
        }
    }
    float ax = ax0 + ax1;
    float ay = ay0 + ay1;
    ax += __shfl_xor(ax, 32);
    ay += __shfl_xor(ay, 32);
    if (half == 0) {
        float a = alpha[wid];
        float2 o; o.x = ax * a; o.y = ay * a;
        *reinterpret_cast<float2*>(out + (size_t)wid * D_FEAT + hl * 2) = o;
    }
}

__global__ void gather_f32(const float* __restrict__ x,
                           const float* __restrict__ alpha,
                           const int* __restrict__ off,
                           const unsigned* __restrict__ csr,
                           float* __restrict__ out, int nnodes) {
    int wid = (blockIdx.x * blockDim.x + threadIdx.x) >> 6;
    int lane = threadIdx.x & 63;
    if (wid >= nnodes) return;
    int beg = off[wid], end = off[wid + 1];
    float acc = 0.0f;
    int i = beg;
    for (; i + 4 <= end; i += 4) {
        unsigned s0 = csr[i + 0], s1 = csr[i + 1], s2 = csr[i + 2], s3 = csr[i + 3];
        float a0 = alpha[s0], a1 = alpha[s1], a2 = alpha[s2], a3 = alpha[s3];
        float v0 = x[(size_t)s0 * D_FEAT + lane];
        float v1 = x[(size_t)s1 * D_FEAT + lane];
        float v2 = x[(size_t)s2 * D_FEAT + lane];
        float v3 = x[(size_t)s3 * D_FEAT + lane];
        acc += v0 * a0; acc += v1 * a1; acc += v2 * a2; acc += v3 * a3;
    }
    for (; i < end; ++i) {
        unsigned s = csr[i];
        acc += x[(size_t)s * D_FEAT + lane] * alpha[s];
    }
    out[(size_t)wid * D_FEAT + lane] = acc * alpha[wid];
}

extern "C" void kernel_launch(void* const* d_in, const int* in_sizes, int n_in,
                              void* d_out, int out_size, void* d_ws, size_t ws_size,
                              hipStream_t stream) {
    const float* x        = (const float*)d_in[0];
    const int*   edge_src = (const int*)d_in[1];
    const int*   edge_dst = (const int*)d_in[2];
    const float* edge_div = (const float*)d_in[3];
    float* out = (float*)d_out;

    int nedges = in_sizes[1];            // 2E
    int nnodes = out_size / D_FEAT;      // N_NODES
    int nbkt   = (nnodes + NPBKT - 1) >> BSH;

    size_t int_words  = (size_t)4 * nnodes + 1 + 1024 + MAXB + 2 * (size_t)nedges;
    size_t xs_bytes   = (size_t)nnodes * D_FEAT * 2;      // bf16 prescaled x
    size_t need_f32   = int_words * 4;
    size_t need_bf16  = xs_bytes + need_f32;

    if (nnodes > 262144 || nbkt > MAXB || ws_size < need_f32) {
        hipMemsetAsync(out, 0, (size_t)out_size * sizeof(float), stream);
        long long total = (long long)nedges * 16;
        radj_scatter_kernel<<<(int)((total + 255) / 256), 256, 0, stream>>>(
            x, edge_src, edge_dst, edge_div, out, nedges);
        return;
    }
    bool use_bf16 = (ws_size >= need_bf16);

    // xs FIRST so its rows are 128B-aligned (d_ws is allocation-aligned).
    unsigned short* xs = (unsigned short*)d_ws;
    char* ibase = (char*)d_ws + (use_bf16 ? xs_bytes : 0);

    int*      deg    = (int*)ibase;                  // n
    int*      incl   = deg + nnodes;                 // n
    int*      off    = incl + nnodes;                // n+1
    float*    alpha  = (float*)(off + nnodes + 1);   // n
    int*      bsums  = (int*)(alpha + nnodes);       // 1024
    int*      gcur   = bsums + 1024;                 // MAXB
    unsigned* binned = (unsigned*)(gcur + MAXB);     // E
    unsigned* csr    = binned + nedges;              // E

    int nblk = (nnodes + SCAN_B - 1) / SCAN_B;

    hipMemsetAsync(deg, 0, (size_t)nnodes * sizeof(int), stream);

    count_deg<<<(nedges + 255) / 256, 256, 0, stream>>>(edge_dst, deg, nedges);

    scan_block<<<nblk, SCAN_B, 0, stream>>>(deg, incl, bsums, nnodes);
    scan_block<<<1, SCAN_B, 0, stream>>>(bsums, bsums, nullptr, nblk);
    scan_finalize<<<nblk, SCAN_B, 0, stream>>>(deg, incl, bsums, off, alpha, nnodes);

    init_gcur<<<(nbkt + 255) / 256, 256, 0, stream>>>(off, gcur, nbkt, nnodes);

    bin_edges<<<(nedges + EPB - 1) / EPB, BIN_T, 0, stream>>>(
        edge_src, edge_dst, gcur, binned, nedges, nbkt);

    build_csr<<<nbkt, NPBKT, 0, stream>>>(off, binned, csr, nnodes);

    long long gthreads = (long long)nnodes * 64;
    int ggrid = (int)((gthreads + 255) / 256);
    if (use_bf16) {
        int n4 = nnodes * (D_FEAT / 4);
        prescale_bf16<<<(n4 + 255) / 256, 256, 0, stream>>>(
            (const float4*)x, alpha, (ushort4*)xs, n4);
        gather_bf16<<<ggrid, 256, 0, stream>>>(xs, alpha, off, csr, out, nnodes);
    } else {
        gather_f32<<<ggrid, 256, 0, stream>>>(x, alpha, off, csr, out, nnodes);
    }
}

// Round 7
// 146.378 us; speedup vs baseline: 8.1972x; 1.5217x over previous
//
#include <hip/hip_runtime.h>

// rAdjConv: out[dst] += x[src] / edge_div over 64 features per edge.
// Round 7: alpha = rsqrt(deg); out[d] = alpha[d] * sum alpha[s]*x[s].
//   No node-granular global atomics anywhere:
//     coarse_count: LDS histogram over 586 coarse buckets (256 nodes each)
//     bucket_scan : 1-block scan of bucket counts -> bucket offsets
//     bin_edges   : block-aggregated binning into contiguous bucket runs
//     build_csr_deg: per-bucket LDS degree count + local scan -> off/alpha/CSR
//     prescale    : xs = bf16(alpha[s]*x[s]), 128B-aligned rows (ws offset 0)
//     gather      : one wave per node, half-wave ushort2 loads, shfl combine

constexpr int D_FEAT = 64;
constexpr int SCAN_B = 1024;
constexpr int BSH    = 8;            // 256 nodes per bucket
constexpr int NPBKT  = 1 << BSH;
constexpr int MAXB   = 1024;         // max buckets (nnodes <= 262144)
constexpr int BIN_T  = 256;
constexpr int BIN_K  = 32;
constexpr int EPB    = BIN_T * BIN_K;  // 8192 edges per bin block

__device__ __forceinline__ unsigned short f2bf(float v) {
    unsigned u = __float_as_uint(v);
    return (unsigned short)((u + 0x7fffu + ((u >> 16) & 1u)) >> 16);
}
__device__ __forceinline__ float bf2f(unsigned short u) {
    return __uint_as_float(((unsigned)u) << 16);
}

// ---------- fallback (round-1 atomic scatter) ----------
__global__ void radj_scatter_kernel(const float* __restrict__ x,
                                    const int* __restrict__ edge_src,
                                    const int* __restrict__ edge_dst,
                                    const float* __restrict__ edge_div,
                                    float* __restrict__ out,
                                    int nedges) {
    long long tid = (long long)blockIdx.x * blockDim.x + threadIdx.x;
    long long total = (long long)nedges * 16;
    if (tid >= total) return;
    int e  = (int)(tid >> 4);
    int fg = (int)(tid & 15) << 2;
    int s = edge_src[e];
    int d = edge_dst[e];
    float inv = 1.0f / edge_div[e];
    const float4 v = *reinterpret_cast<const float4*>(x + (long long)s * D_FEAT + fg);
    float* o = out + (long long)d * D_FEAT + fg;
    atomicAdd(o + 0, v.x * inv);
    atomicAdd(o + 1, v.y * inv);
    atomicAdd(o + 2, v.z * inv);
    atomicAdd(o + 3, v.w * inv);
}

// ---------- pass A: coarse bucket histogram (LDS-aggregated) ----------
__global__ __launch_bounds__(BIN_T) void coarse_count(
    const int* __restrict__ dst, int* __restrict__ cnt, int n, int nbkt) {
    __shared__ int h[MAXB];
    for (int t = threadIdx.x; t < nbkt; t += BIN_T) h[t] = 0;
    __syncthreads();
    long long e0 = (long long)blockIdx.x * EPB;
#pragma unroll
    for (int k = 0; k < BIN_K; ++k) {
        long long e = e0 + (long long)k * BIN_T + threadIdx.x;
        if (e < n) atomicAdd(&h[dst[e] >> BSH], 1);
    }
    __syncthreads();
    for (int t = threadIdx.x; t < nbkt; t += BIN_T)
        if (h[t]) atomicAdd(&cnt[t], h[t]);
}

// ---------- scan of bucket counts (single block, nbkt <= 1024) ----------
__global__ __launch_bounds__(SCAN_B) void bucket_scan(
    const int* __restrict__ cnt, int* __restrict__ boff,
    int* __restrict__ gcur, int nbkt) {
    __shared__ int tmp[SCAN_B];
    int tid = threadIdx.x;
    int v = (tid < nbkt) ? cnt[tid] : 0;
    tmp[tid] = v;
    __syncthreads();
    for (int ofs = 1; ofs < SCAN_B; ofs <<= 1) {
        int t = (tid >= ofs) ? tmp[tid - ofs] : 0;
        __syncthreads();
        tmp[tid] += t;
        __syncthreads();
    }
    int excl = tmp[tid] - v;
    if (tid < nbkt) { boff[tid] = excl; gcur[tid] = excl; }
    if (tid == nbkt - 1) boff[nbkt] = excl + v;
}

// ---------- pass B: block-aggregated coarse binning ----------
// binned entry = (dstLocal<<18) | src  (src < 2^18, dstLocal < 256)
__global__ __launch_bounds__(BIN_T) void bin_edges(
    const int* __restrict__ src, const int* __restrict__ dst,
    int* __restrict__ gcur, unsigned* __restrict__ binned, int n, int nbkt) {
    __shared__ int hist[MAXB];
    __shared__ int base[MAXB];
    __shared__ unsigned einfo[EPB];   // (b<<13) | rank
    for (int t = threadIdx.x; t < nbkt; t += BIN_T) hist[t] = 0;
    __syncthreads();
    long long e0 = (long long)blockIdx.x * EPB;
#pragma unroll
    for (int k = 0; k < BIN_K; ++k) {
        long long e = e0 + (long long)k * BIN_T + threadIdx.x;
        if (e < n) {
            int b = dst[e] >> BSH;
            int rank = atomicAdd(&hist[b], 1);
            einfo[k * BIN_T + threadIdx.x] = ((unsigned)b << 13) | (unsigned)rank;
        }
    }
    __syncthreads();
    for (int t = threadIdx.x; t < nbkt; t += BIN_T) {
        int h = hist[t];
        base[t] = h ? atomicAdd(&gcur[t], h) : 0;
    }
    __syncthreads();
#pragma unroll
    for (int k = 0; k < BIN_K; ++k) {
        long long e = e0 + (long long)k * BIN_T + threadIdx.x;
        if (e < n) {
            int d = dst[e];
            int s = src[e];
            unsigned info = einfo[k * BIN_T + threadIdx.x];
            int b = info >> 13;
            int rank = info & 0x1fff;
            binned[base[b] + rank] = ((unsigned)(d & (NPBKT - 1)) << 18) | (unsigned)s;
        }
    }
}

// ---------- pass C: per-bucket degree + local scan + exact CSR ----------
__global__ __launch_bounds__(NPBKT) void build_csr_deg(
    const int* __restrict__ boff, const unsigned* __restrict__ binned,
    unsigned* __restrict__ csr, int* __restrict__ off, float* __restrict__ alpha,
    int nnodes, int nbkt) {
    __shared__ int h[NPBKT];
    __shared__ int tmp[NPBKT];
    __shared__ int cur[NPBKT];
    int tid = threadIdx.x;
    int lo = blockIdx.x << BSH;
    int hi = lo + NPBKT; if (hi > nnodes) hi = nnodes;
    int beg = boff[blockIdx.x], end = boff[blockIdx.x + 1];
    h[tid] = 0;
    __syncthreads();
    for (int i = beg + tid; i < end; i += NPBKT)
        atomicAdd(&h[binned[i] >> 18], 1);
    __syncthreads();
    int deg = h[tid];
    tmp[tid] = deg;
    __syncthreads();
    for (int ofs = 1; ofs < NPBKT; ofs <<= 1) {
        int t = (tid >= ofs) ? tmp[tid - ofs] : 0;
        __syncthreads();
        tmp[tid] += t;
        __syncthreads();
    }
    int excl = tmp[tid] - deg;
    cur[tid] = beg + excl;
    if (lo + tid < hi) {
        off[lo + tid] = beg + excl;
        alpha[lo + tid] = rsqrtf(fmaxf((float)deg, 1.0f));
    }
    if (blockIdx.x == nbkt - 1 && tid == 0) off[nnodes] = end;
    __syncthreads();
    for (int i = beg + tid; i < end; i += NPBKT) {
        unsigned p = binned[i];
        int pos = atomicAdd(&cur[p >> 18], 1);
        csr[pos] = p & 0x3ffffu;
    }
}

// ---------- prescale x by alpha[src], cast to bf16 ----------
__global__ void prescale_bf16(const float4* __restrict__ x4,
                              const float* __restrict__ alpha,
                              ushort4* __restrict__ xs4, int n4) {
    int g = blockIdx.x * blockDim.x + threadIdx.x;
    if (g >= n4) return;
    float a = alpha[g >> 4];
    float4 v = x4[g];
    ushort4 o;
    o.x = f2bf(v.x * a);
    o.y = f2bf(v.y * a);
    o.z = f2bf(v.z * a);
    o.w = f2bf(v.w * a);
    xs4[g] = o;
}

// ---------- gather: one wave per node, half-wave ushort2 loads ----------
__global__ void gather_bf16(const unsigned short* __restrict__ xs,
                            const float* __restrict__ alpha,
                            const int* __restrict__ off,
                            const unsigned* __restrict__ csr,
                            float* __restrict__ out, int nnodes) {
    int wid = (blockIdx.x * blockDim.x + threadIdx.x) >> 6;
    if (wid >= nnodes) return;
    int lane = threadIdx.x & 63;
    int half = lane >> 5;      // 0: even edges, 1: odd edges
    int hl   = lane & 31;      // feature pair index
    int beg = off[wid], end = off[wid + 1];
    const unsigned short* xb = xs + hl * 2;
    float ax0 = 0.f, ay0 = 0.f, ax1 = 0.f, ay1 = 0.f;
    int j = beg;
    for (; j + 8 <= end; j += 8) {
        int i0 = j + half, i1 = i0 + 2, i2 = i0 + 4, i3 = i0 + 6;
        unsigned s0 = csr[i0], s1 = csr[i1], s2 = csr[i2], s3 = csr[i3];
        ushort2 u0 = *reinterpret_cast<const ushort2*>(xb + (size_t)s0 * D_FEAT);
        ushort2 u1 = *reinterpret_cast<const ushort2*>(xb + (size_t)s1 * D_FEAT);
        ushort2 u2 = *reinterpret_cast<const ushort2*>(xb + (size_t)s2 * D_FEAT);
        ushort2 u3 = *reinterpret_cast<const ushort2*>(xb + (size_t)s3 * D_FEAT);
        ax0 += bf2f(u0.x); ay0 += bf2f(u0.y);
        ax1 += bf2f(u1.x); ay1 += bf2f(u1.y);
        ax0 += bf2f(u2.x); ay0 += bf2f(u2.y);
        ax1 += bf2f(u3.x); ay1 += bf2f(u3.y);
    }
    for (; j < end; j += 2) {
        int i = j + half;
        if (i < end) {
            unsigned s = csr[i];
            ushort2 u = *reinterpret_cast<const ushort2*>(xb + (size_t)s * D_FEAT);
            ax0 += bf2f(u.x); ay0 += bf2f(u.y);
        }
    }
    float ax = ax0 + ax1;
    float ay = ay0 + ay1;
    ax += __shfl_xor(ax, 32);
    ay += __shfl_xor(ay, 32);
    if (half == 0) {
        float a = alpha[wid];
        float2 o; o.x = ax * a; o.y = ay * a;
        *reinterpret_cast<float2*>(out + (size_t)wid * D_FEAT + hl * 2) = o;
    }
}

__global__ void gather_f32(const float* __restrict__ x,
                           const float* __restrict__ alpha,
                           const int* __restrict__ off,
                           const unsigned* __restrict__ csr,
                           float* __restrict__ out, int nnodes) {
    int wid = (blockIdx.x * blockDim.x + threadIdx.x) >> 6;
    int lane = threadIdx.x & 63;
    if (wid >= nnodes) return;
    int beg = off[wid], end = off[wid + 1];
    float acc = 0.0f;
    int i = beg;
    for (; i + 4 <= end; i += 4) {
        unsigned s0 = csr[i + 0], s1 = csr[i + 1], s2 = csr[i + 2], s3 = csr[i + 3];
        float a0 = alpha[s0], a1 = alpha[s1], a2 = alpha[s2], a3 = alpha[s3];
        float v0 = x[(size_t)s0 * D_FEAT + lane];
        float v1 = x[(size_t)s1 * D_FEAT + lane];
        float v2 = x[(size_t)s2 * D_FEAT + lane];
        float v3 = x[(size_t)s3 * D_FEAT + lane];
        acc += v0 * a0; acc += v1 * a1; acc += v2 * a2; acc += v3 * a3;
    }
    for (; i < end; ++i) {
        unsigned s = csr[i];
        acc += x[(size_t)s * D_FEAT + lane] * alpha[s];
    }
    out[(size_t)wid * D_FEAT + lane] = acc * alpha[wid];
}

extern "C" void kernel_launch(void* const* d_in, const int* in_sizes, int n_in,
                              void* d_out, int out_size, void* d_ws, size_t ws_size,
                              hipStream_t stream) {
    const float* x        = (const float*)d_in[0];
    const int*   edge_src = (const int*)d_in[1];
    const int*   edge_dst = (const int*)d_in[2];
    const float* edge_div = (const float*)d_in[3];
    float* out = (float*)d_out;

    int nedges = in_sizes[1];            // 2E
    int nnodes = out_size / D_FEAT;      // N_NODES
    int nbkt   = (nnodes + NPBKT - 1) >> BSH;

    size_t xs_bytes  = (size_t)nnodes * D_FEAT * 2;   // bf16 prescaled x
    size_t int_words = (size_t)(3 * MAXB + 1) + 2 * (size_t)nnodes + 2
                     + 2 * (size_t)nedges;
    size_t need_f32  = int_words * 4;
    size_t need_bf16 = xs_bytes + need_f32;

    if (nnodes > 262144 || nbkt > MAXB || ws_size < need_f32) {
        hipMemsetAsync(out, 0, (size_t)out_size * sizeof(float), stream);
        long long total = (long long)nedges * 16;
        radj_scatter_kernel<<<(int)((total + 255) / 256), 256, 0, stream>>>(
            x, edge_src, edge_dst, edge_div, out, nedges);
        return;
    }
    bool use_bf16 = (ws_size >= need_bf16);

    // xs FIRST so its rows are 128B-aligned (d_ws is allocation-aligned).
    unsigned short* xs = (unsigned short*)d_ws;
    int* ibase = (int*)((char*)d_ws + (use_bf16 ? xs_bytes : 0));

    int*      cnt    = ibase;                 // MAXB
    int*      boff   = cnt + MAXB;            // MAXB + 1
    int*      gcur   = boff + MAXB + 1;       // MAXB
    int*      off    = gcur + MAXB;           // n + 1
    float*    alpha  = (float*)(off + nnodes + 1);  // n
    unsigned* binned = (unsigned*)(alpha + nnodes); // E
    unsigned* csr    = binned + nedges;             // E

    int ebks = (nedges + EPB - 1) / EPB;

    hipMemsetAsync(cnt, 0, (size_t)MAXB * sizeof(int), stream);

    coarse_count<<<ebks, BIN_T, 0, stream>>>(edge_dst, cnt, nedges, nbkt);

    bucket_scan<<<1, SCAN_B, 0, stream>>>(cnt, boff, gcur, nbkt);

    bin_edges<<<ebks, BIN_T, 0, stream>>>(
        edge_src, edge_dst, gcur, binned, nedges, nbkt);

    build_csr_deg<<<nbkt, NPBKT, 0, stream>>>(
        boff, binned, csr, off, alpha, nnodes, nbkt);

    long long gthreads = (long long)nnodes * 64;
    int ggrid = (int)((gthreads + 255) / 256);
    if (use_bf16) {
        int n4 = nnodes * (D_FEAT / 4);
        prescale_bf16<<<(n4 + 255) / 256, 256, 0, stream>>>(
            (const float4*)x, alpha, (ushort4*)xs, n4);
        gather_bf16<<<ggrid, 256, 0, stream>>>(xs, alpha, off, csr, out, nnodes);
    } else {
        gather_f32<<<ggrid, 256, 0, stream>>>(x, alpha, off, csr, out, nnodes);
    }
}

// Round 8
// 126.463 us; speedup vs baseline: 9.4880x; 1.1575x over previous
//
#include <hip/hip_runtime.h>

// rAdjConv: out[dst] += x[src] / edge_div over 64 features per edge.
// Round 8: alpha = rsqrt(deg); out[d] = alpha[d] * sum alpha[s]*x[s].
//   coarse_count : LDS histogram over coarse buckets (256 nodes each)
//   bucket_scan  : 1-block scan of bucket counts -> bucket offsets
//   bin_edges    : block-aggregated binning into contiguous bucket runs
//   build_csr_deg: per-bucket degree + local scan -> off/alpha/CSR
//                  + fused prescale xs = bf16(alpha[s]*x[s]) for own nodes
//   gather       : one wave per node; csr indices preloaded coalesced into
//                  lanes + __shfl distribute; 16-lane ushort4 row loads
//                  (4 edges per VMEM instr), mask-FMA tail, shfl_xor reduce.

constexpr int D_FEAT = 64;
constexpr int SCAN_B = 1024;
constexpr int BSH    = 8;            // 256 nodes per bucket
constexpr int NPBKT  = 1 << BSH;
constexpr int MAXB   = 1024;         // max buckets (nnodes <= 262144)
constexpr int BIN_T  = 256;
constexpr int BIN_K  = 32;
constexpr int EPB    = BIN_T * BIN_K;  // 8192 edges per bin block

__device__ __forceinline__ unsigned short f2bf(float v) {
    unsigned u = __float_as_uint(v);
    return (unsigned short)((u + 0x7fffu + ((u >> 16) & 1u)) >> 16);
}
__device__ __forceinline__ float bf2f(unsigned short u) {
    return __uint_as_float(((unsigned)u) << 16);
}

// ---------- fallback (round-1 atomic scatter) ----------
__global__ void radj_scatter_kernel(const float* __restrict__ x,
                                    const int* __restrict__ edge_src,
                                    const int* __restrict__ edge_dst,
                                    const float* __restrict__ edge_div,
                                    float* __restrict__ out,
                                    int nedges) {
    long long tid = (long long)blockIdx.x * blockDim.x + threadIdx.x;
    long long total = (long long)nedges * 16;
    if (tid >= total) return;
    int e  = (int)(tid >> 4);
    int fg = (int)(tid & 15) << 2;
    int s = edge_src[e];
    int d = edge_dst[e];
    float inv = 1.0f / edge_div[e];
    const float4 v = *reinterpret_cast<const float4*>(x + (long long)s * D_FEAT + fg);
    float* o = out + (long long)d * D_FEAT + fg;
    atomicAdd(o + 0, v.x * inv);
    atomicAdd(o + 1, v.y * inv);
    atomicAdd(o + 2, v.z * inv);
    atomicAdd(o + 3, v.w * inv);
}

// ---------- pass A: coarse bucket histogram (LDS-aggregated) ----------
__global__ __launch_bounds__(BIN_T) void coarse_count(
    const int* __restrict__ dst, int* __restrict__ cnt, int n, int nbkt) {
    __shared__ int h[MAXB];
    for (int t = threadIdx.x; t < nbkt; t += BIN_T) h[t] = 0;
    __syncthreads();
    long long e0 = (long long)blockIdx.x * EPB;
#pragma unroll
    for (int k = 0; k < BIN_K; ++k) {
        long long e = e0 + (long long)k * BIN_T + threadIdx.x;
        if (e < n) atomicAdd(&h[dst[e] >> BSH], 1);
    }
    __syncthreads();
    for (int t = threadIdx.x; t < nbkt; t += BIN_T)
        if (h[t]) atomicAdd(&cnt[t], h[t]);
}

// ---------- scan of bucket counts (single block, nbkt <= 1024) ----------
__global__ __launch_bounds__(SCAN_B) void bucket_scan(
    const int* __restrict__ cnt, int* __restrict__ boff,
    int* __restrict__ gcur, int nbkt) {
    __shared__ int tmp[SCAN_B];
    int tid = threadIdx.x;
    int v = (tid < nbkt) ? cnt[tid] : 0;
    tmp[tid] = v;
    __syncthreads();
    for (int ofs = 1; ofs < SCAN_B; ofs <<= 1) {
        int t = (tid >= ofs) ? tmp[tid - ofs] : 0;
        __syncthreads();
        tmp[tid] += t;
        __syncthreads();
    }
    int excl = tmp[tid] - v;
    if (tid < nbkt) { boff[tid] = excl; gcur[tid] = excl; }
    if (tid == nbkt - 1) boff[nbkt] = excl + v;
}

// ---------- pass B: block-aggregated coarse binning ----------
// binned entry = (dstLocal<<18) | src  (src < 2^18, dstLocal < 256)
__global__ __launch_bounds__(BIN_T) void bin_edges(
    const int* __restrict__ src, const int* __restrict__ dst,
    int* __restrict__ gcur, unsigned* __restrict__ binned, int n, int nbkt) {
    __shared__ int hist[MAXB];
    __shared__ int base[MAXB];
    __shared__ unsigned einfo[EPB];   // (b<<13) | rank
    for (int t = threadIdx.x; t < nbkt; t += BIN_T) hist[t] = 0;
    __syncthreads();
    long long e0 = (long long)blockIdx.x * EPB;
#pragma unroll
    for (int k = 0; k < BIN_K; ++k) {
        long long e = e0 + (long long)k * BIN_T + threadIdx.x;
        if (e < n) {
            int b = dst[e] >> BSH;
            int rank = atomicAdd(&hist[b], 1);
            einfo[k * BIN_T + threadIdx.x] = ((unsigned)b << 13) | (unsigned)rank;
        }
    }
    __syncthreads();
    for (int t = threadIdx.x; t < nbkt; t += BIN_T) {
        int h = hist[t];
        base[t] = h ? atomicAdd(&gcur[t], h) : 0;
    }
    __syncthreads();
#pragma unroll
    for (int k = 0; k < BIN_K; ++k) {
        long long e = e0 + (long long)k * BIN_T + threadIdx.x;
        if (e < n) {
            int d = dst[e];
            int s = src[e];
            unsigned info = einfo[k * BIN_T + threadIdx.x];
            int b = info >> 13;
            int rank = info & 0x1fff;
            binned[base[b] + rank] = ((unsigned)(d & (NPBKT - 1)) << 18) | (unsigned)s;
        }
    }
}

// ---------- pass C: per-bucket degree + local scan + exact CSR + prescale ----------
__global__ __launch_bounds__(NPBKT) void build_csr_deg(
    const int* __restrict__ boff, const unsigned* __restrict__ binned,
    unsigned* __restrict__ csr, int* __restrict__ off, float* __restrict__ alpha,
    const float4* __restrict__ x4, ushort4* __restrict__ xs4,
    int nnodes, int nbkt) {
    __shared__ int h[NPBKT];
    __shared__ int tmp[NPBKT];
    __shared__ int cur[NPBKT];
    __shared__ float ash[NPBKT];
    int tid = threadIdx.x;
    int lo = blockIdx.x << BSH;
    int hi = lo + NPBKT; if (hi > nnodes) hi = nnodes;
    int beg = boff[blockIdx.x], end = boff[blockIdx.x + 1];
    h[tid] = 0;
    __syncthreads();
    for (int i = beg + tid; i < end; i += NPBKT)
        atomicAdd(&h[binned[i] >> 18], 1);
    __syncthreads();
    int deg = h[tid];
    tmp[tid] = deg;
    __syncthreads();
    for (int ofs = 1; ofs < NPBKT; ofs <<= 1) {
        int t = (tid >= ofs) ? tmp[tid - ofs] : 0;
        __syncthreads();
        tmp[tid] += t;
        __syncthreads();
    }
    int excl = tmp[tid] - deg;
    cur[tid] = beg + excl;
    float a = rsqrtf(fmaxf((float)deg, 1.0f));
    ash[tid] = a;
    if (lo + tid < hi) {
        off[lo + tid] = beg + excl;
        alpha[lo + tid] = a;
    }
    if (blockIdx.x == nbkt - 1 && tid == 0) off[nnodes] = end;
    __syncthreads();
    for (int i = beg + tid; i < end; i += NPBKT) {
        unsigned p = binned[i];
        int pos = atomicAdd(&cur[p >> 18], 1);
        csr[pos] = p & 0x3ffffu;
    }
    if (xs4) {
        // prescale this bucket's rows: 16 float4 per node, coalesced
        const float4* xrow = x4 + ((size_t)lo << 4);
        ushort4* orow = xs4 + ((size_t)lo << 4);
        int nf4 = (hi - lo) << 4;
        for (int t = tid; t < nf4; t += NPBKT) {
            float av = ash[t >> 4];
            float4 v = xrow[t];
            ushort4 o;
            o.x = f2bf(v.x * av);
            o.y = f2bf(v.y * av);
            o.z = f2bf(v.z * av);
            o.w = f2bf(v.w * av);
            orow[t] = o;
        }
    }
}

// ---------- gather: one wave per node, preloaded indices, 16-lane rows ----------
__global__ __launch_bounds__(256) void gather_bf16(
    const unsigned short* __restrict__ xs,
    const float* __restrict__ alpha,
    const int* __restrict__ off,
    const unsigned* __restrict__ csr,
    float* __restrict__ out, int nnodes) {
    int wid = (blockIdx.x * blockDim.x + threadIdx.x) >> 6;
    if (wid >= nnodes) return;
    int lane = threadIdx.x & 63;
    int eg = lane >> 4;        // edge slot 0..3
    int fl = lane & 15;        // feature group: feats fl*4 .. fl*4+3
    int beg = off[wid], end = off[wid + 1];
    int degree = end - beg;
    float a0 = 0.f, a1 = 0.f, a2 = 0.f, a3 = 0.f;
    const unsigned short* xb = xs + (fl << 2);
    for (int base = 0; base < degree; base += 64) {
        int nchunk = degree - base; if (nchunk > 64) nchunk = 64;
        // coalesced index preload (clamped lanes duplicate last valid index)
        int l = lane < nchunk ? lane : nchunk - 1;
        int idx = (int)csr[beg + base + l];
        for (int j = 0; j < nchunk; j += 8) {
            int j0 = j + eg, j1 = j0 + 4;
            int s0 = __shfl(idx, j0);
            int s1 = __shfl(idx, j1);
            float m0 = (j0 < nchunk) ? 1.f : 0.f;
            float m1 = (j1 < nchunk) ? 1.f : 0.f;
            ushort4 u0 = *reinterpret_cast<const ushort4*>(xb + ((size_t)s0 << 6));
            ushort4 u1 = *reinterpret_cast<const ushort4*>(xb + ((size_t)s1 << 6));
            a0 = fmaf(m0, bf2f(u0.x), a0);
            a1 = fmaf(m0, bf2f(u0.y), a1);
            a2 = fmaf(m0, bf2f(u0.z), a2);
            a3 = fmaf(m0, bf2f(u0.w), a3);
            a0 = fmaf(m1, bf2f(u1.x), a0);
            a1 = fmaf(m1, bf2f(u1.y), a1);
            a2 = fmaf(m1, bf2f(u1.z), a2);
            a3 = fmaf(m1, bf2f(u1.w), a3);
        }
    }
    // reduce across the 4 edge slots (lanes differ in bits 4 and 5)
    a0 += __shfl_xor(a0, 16); a1 += __shfl_xor(a1, 16);
    a2 += __shfl_xor(a2, 16); a3 += __shfl_xor(a3, 16);
    a0 += __shfl_xor(a0, 32); a1 += __shfl_xor(a1, 32);
    a2 += __shfl_xor(a2, 32); a3 += __shfl_xor(a3, 32);
    if (eg == 0) {
        float al = alpha[wid];
        float4 o;
        o.x = a0 * al; o.y = a1 * al; o.z = a2 * al; o.w = a3 * al;
        *reinterpret_cast<float4*>(out + ((size_t)wid << 6) + (fl << 2)) = o;
    }
}

__global__ void gather_f32(const float* __restrict__ x,
                           const float* __restrict__ alpha,
                           const int* __restrict__ off,
                           const unsigned* __restrict__ csr,
                           float* __restrict__ out, int nnodes) {
    int wid = (blockIdx.x * blockDim.x + threadIdx.x) >> 6;
    int lane = threadIdx.x & 63;
    if (wid >= nnodes) return;
    int beg = off[wid], end = off[wid + 1];
    float acc = 0.0f;
    int i = beg;
    for (; i + 4 <= end; i += 4) {
        unsigned s0 = csr[i + 0], s1 = csr[i + 1], s2 = csr[i + 2], s3 = csr[i + 3];
        float a0 = alpha[s0], a1 = alpha[s1], a2 = alpha[s2], a3 = alpha[s3];
        float v0 = x[(size_t)s0 * D_FEAT + lane];
        float v1 = x[(size_t)s1 * D_FEAT + lane];
        float v2 = x[(size_t)s2 * D_FEAT + lane];
        float v3 = x[(size_t)s3 * D_FEAT + lane];
        acc += v0 * a0; acc += v1 * a1; acc += v2 * a2; acc += v3 * a3;
    }
    for (; i < end; ++i) {
        unsigned s = csr[i];
        acc += x[(size_t)s * D_FEAT + lane] * alpha[s];
    }
    out[(size_t)wid * D_FEAT + lane] = acc * alpha[wid];
}

extern "C" void kernel_launch(void* const* d_in, const int* in_sizes, int n_in,
                              void* d_out, int out_size, void* d_ws, size_t ws_size,
                              hipStream_t stream) {
    const float* x        = (const float*)d_in[0];
    const int*   edge_src = (const int*)d_in[1];
    const int*   edge_dst = (const int*)d_in[2];
    const float* edge_div = (const float*)d_in[3];
    float* out = (float*)d_out;

    int nedges = in_sizes[1];            // 2E
    int nnodes = out_size / D_FEAT;      // N_NODES
    int nbkt   = (nnodes + NPBKT - 1) >> BSH;

    size_t xs_bytes  = (size_t)nnodes * D_FEAT * 2;   // bf16 prescaled x
    size_t int_words = (size_t)(3 * MAXB + 1) + 2 * (size_t)nnodes + 2
                     + 2 * (size_t)nedges;
    size_t need_f32  = int_words * 4;
    size_t need_bf16 = xs_bytes + need_f32;

    if (nnodes > 262144 || nbkt > MAXB || ws_size < need_f32) {
        hipMemsetAsync(out, 0, (size_t)out_size * sizeof(float), stream);
        long long total = (long long)nedges * 16;
        radj_scatter_kernel<<<(int)((total + 255) / 256), 256, 0, stream>>>(
            x, edge_src, edge_dst, edge_div, out, nedges);
        return;
    }
    bool use_bf16 = (ws_size >= need_bf16);

    // xs FIRST so its rows are 128B-aligned (d_ws is allocation-aligned).
    unsigned short* xs = (unsigned short*)d_ws;
    int* ibase = (int*)((char*)d_ws + (use_bf16 ? xs_bytes : 0));

    int*      cnt    = ibase;                 // MAXB
    int*      boff   = cnt + MAXB;            // MAXB + 1
    int*      gcur   = boff + MAXB + 1;       // MAXB
    int*      off    = gcur + MAXB;           // n + 1
    float*    alpha  = (float*)(off + nnodes + 1);  // n
    unsigned* binned = (unsigned*)(alpha + nnodes); // E
    unsigned* csr    = binned + nedges;             // E

    int ebks = (nedges + EPB - 1) / EPB;

    hipMemsetAsync(cnt, 0, (size_t)MAXB * sizeof(int), stream);

    coarse_count<<<ebks, BIN_T, 0, stream>>>(edge_dst, cnt, nedges, nbkt);

    bucket_scan<<<1, SCAN_B, 0, stream>>>(cnt, boff, gcur, nbkt);

    bin_edges<<<ebks, BIN_T, 0, stream>>>(
        edge_src, edge_dst, gcur, binned, nedges, nbkt);

    build_csr_deg<<<nbkt, NPBKT, 0, stream>>>(
        boff, binned, csr, off, alpha,
        (const float4*)x, use_bf16 ? (ushort4*)xs : nullptr,
        nnodes, nbkt);

    long long gthreads = (long long)nnodes * 64;
    int ggrid = (int)((gthreads + 255) / 256);
    if (use_bf16) {
        gather_bf16<<<ggrid, 256, 0, stream>>>(xs, alpha, off, csr, out, nnodes);
    } else {
        gather_f32<<<ggrid, 256, 0, stream>>>(x, alpha, off, csr, out, nnodes);
    }
}